// Round 3
// baseline (195.828 us; speedup 1.0000x reference)
//
#include <hip/hip_runtime.h>
#include <math.h>

#define BB 4
#define CC 256
#define LL 4096
#define DD 32   // q/k channels
#define LOG2E 1.44269504088896f

typedef __attribute__((ext_vector_type(8))) short short8;   // 8 bf16 (4 VGPRs)
typedef __attribute__((ext_vector_type(4))) short short4v;
typedef __attribute__((ext_vector_type(4))) float f32x4;
typedef __attribute__((ext_vector_type(4))) unsigned int uint4v;
typedef __attribute__((ext_vector_type(2))) unsigned int uint2v;

// raw workgroup barrier: waits LDS ops only — global prefetches stay in flight
#define BARRIER() asm volatile("s_waitcnt lgkmcnt(0)\n\ts_barrier" ::: "memory")

__device__ inline unsigned short f2bf(float f) {
  union { float f; unsigned u; } v; v.f = f;
  unsigned r = v.u + 0x7fffu + ((v.u >> 16) & 1u);  // RNE
  return (unsigned short)(r >> 16);
}

__device__ inline float fast_exp2(float x) {
#if __has_builtin(__builtin_amdgcn_exp2f)
  return __builtin_amdgcn_exp2f(x);
#else
  return exp2f(x);
#endif
}

// natural key p -> kT storage row within its 32-key group (P C-layout == PV B-layout)
__device__ __host__ inline int sigma32(int p) {
  const int q4 = (p >> 3) & 3, u = p & 7;
  return 16 * (u >> 2) + 4 * q4 + (u & 3);
}

// ---------------- kernel 0: W -> bf16 MFMA-fragment-linear layout ----------------
// wf[ot(20)][ks(8)][lane(64)][8]; Wq rows pre-scaled by log2(e).
__global__ __launch_bounds__(256) void wprep_kernel(
    const float* __restrict__ Wq, const float* __restrict__ Wk, const float* __restrict__ Wv,
    unsigned short* __restrict__ wf)
{
  const int t = threadIdx.x;
  const int ot = blockIdx.x >> 1;           // 0..19
  const int rep = blockIdx.x & 1;
  const int lane = t & 63, cl = lane & 15, q4 = lane >> 4;
  const int ks = (t >> 6) + 4 * rep;        // 0..7
  const int o = ot * 16 + cl;
  const int c = ks * 32 + q4 * 8;
  const float* src = (o < 32) ? (Wq + o * CC) : (o < 64) ? (Wk + (o - 32) * CC)
                                              : (Wv + (o - 64) * CC);
  const float sc = (o < 32) ? LOG2E : 1.0f;
  unsigned short p[8];
  #pragma unroll
  for (int j = 0; j < 8; ++j) p[j] = f2bf(src[c + j] * sc);
  uint4v u;
  u.x = (unsigned)p[0] | ((unsigned)p[1] << 16);
  u.y = (unsigned)p[2] | ((unsigned)p[3] << 16);
  u.z = (unsigned)p[4] | ((unsigned)p[5] << 16);
  u.w = (unsigned)p[6] | ((unsigned)p[7] << 16);
  *(uint4v*)(wf + ((size_t)(ot * 8 + ks) * 64 + lane) * 8) = u;
}

// ---------------- kernel 1: fused transpose + QKV projection (R6-proven) ----------------
// grid 512 = (b, it 32-i tile) XCD-affine; 512 thr = 8 waves (wi 16-i, wo 5-ot).
__global__ __launch_bounds__(512, 4) void qkv_kernel(
    const float* __restrict__ x, const unsigned short* __restrict__ wf,
    const float* __restrict__ bq, const float* __restrict__ bk, const float* __restrict__ bv,
    unsigned short* __restrict__ qT, unsigned short* __restrict__ kT,
    unsigned short* __restrict__ vf)
{
  __shared__ union {
    float xl[32 * 261];                                   // [i][c] odd stride
    struct {
      unsigned short qk[32 * 72];                         // [i][o 0..63]
      __align__(16) unsigned short v[256 * 40];           // [ch][key 0..31] pad-40
    } ep;
  } sm;

  const int t = threadIdx.x;
  const int lane = t & 63, cl = lane & 15, q4 = lane >> 4;
  const int blk = blockIdx.x;
  const int b  = (blk & 7) >> 1;                          // XCD-batch affinity
  const int it = ((blk >> 3) << 1) + (blk & 1);           // 0..127
  const int i0 = it * 32;

  // ---- stage x: coalesced 128B rows -> LDS transposed ----
  {
    const int ln8 = t & 7;
    #pragma unroll
    for (int p = 0; p < 4; ++p) {
      const int c = (t >> 3) + 64 * p;
      const f32x4 v = *(const f32x4*)(x + ((size_t)(b * CC + c)) * LL + i0 + ln8 * 4);
      #pragma unroll
      for (int k = 0; k < 4; ++k) sm.xl[(ln8 * 4 + k) * 261 + c] = v[k];
    }
  }
  __syncthreads();

  // ---- GEMM: wave (wi,wo): 80 o-rows x 16 i x 256 c ----
  const int wi = (t >> 6) & 1, wo = t >> 7;
  const f32x4 zero = {0.f, 0.f, 0.f, 0.f};
  f32x4 acc[5];
  #pragma unroll
  for (int u = 0; u < 5; ++u) acc[u] = zero;

  for (int ks = 0; ks < 8; ++ks) {
    unsigned short p[8];
    #pragma unroll
    for (int j = 0; j < 8; ++j)
      p[j] = f2bf(sm.xl[(16 * wi + cl) * 261 + ks * 32 + q4 * 8 + j]);
    union { short8 s; uint4v u; } bfr;
    bfr.u.x = (unsigned)p[0] | ((unsigned)p[1] << 16);
    bfr.u.y = (unsigned)p[2] | ((unsigned)p[3] << 16);
    bfr.u.z = (unsigned)p[4] | ((unsigned)p[5] << 16);
    bfr.u.w = (unsigned)p[6] | ((unsigned)p[7] << 16);
    #pragma unroll
    for (int u = 0; u < 5; ++u) {
      const short8 a = *(const short8*)(wf + ((size_t)((wo * 5 + u) * 8 + ks) * 64 + lane) * 8);
      acc[u] = __builtin_amdgcn_mfma_f32_16x16x32_bf16(a, bfr.s, acc[u], 0, 0, 0);
    }
  }
  __syncthreads();   // xl dead; alias as ep

  // ---- stage outputs ----
  #pragma unroll
  for (int u = 0; u < 5; ++u) {
    const int g = wo * 5 + u;
    if (g < 4) {     // q (g<2) / k
      short4v pk;
      #pragma unroll
      for (int r = 0; r < 4; ++r) {
        const int o = 16 * g + 4 * q4 + r;
        const float v = acc[u][r] + ((o < 32) ? bq[o] * LOG2E : bk[o - 32]);
        pk[r] = (short)f2bf(v);
      }
      *(short4v*)&sm.ep.qk[(16 * wi + cl) * 72 + 16 * g + 4 * q4] = pk;
    } else {
      #pragma unroll
      for (int r = 0; r < 4; ++r) {
        const int ch = 16 * (g - 4) + 4 * q4 + r;
        sm.ep.v[ch * 40 + 16 * wi + cl] = f2bf(acc[u][r] + bv[ch]);
      }
    }
  }
  __syncthreads();

  // ---- coalesced stores ----
  if (t < 64) {
    const int i = t >> 1, which = t & 1;
    const int gi = i0 + i;
    const unsigned short* srcp = &sm.ep.qk[i * 72 + which * 32];
    uint4v d0 = *(const uint4v*)(srcp + 0);
    uint4v d1 = *(const uint4v*)(srcp + 8);
    uint4v d2 = *(const uint4v*)(srcp + 16);
    uint4v d3 = *(const uint4v*)(srcp + 24);
    unsigned short* dst;
    if (which == 0) {
      dst = qT + ((size_t)b * LL + gi) * DD;
    } else {
      const int row = (gi & ~31) + sigma32(gi & 31);
      dst = kT + ((size_t)b * LL + row) * DD;
    }
    *(uint4v*)dst = d0; *(uint4v*)(dst + 8) = d1;
    *(uint4v*)(dst + 16) = d2; *(uint4v*)(dst + 24) = d3;
  }
  // vf: this block covers kk = it&1 of jt = it>>1: 16 frags x 1KB
  const int kk = it & 1, jt = it >> 1;
  #pragma unroll
  for (int rep = 0; rep < 2; ++rep) {
    const int slot = t + 512 * rep;
    const int fl = slot >> 6, l2 = slot & 63;
    const int cl2 = l2 & 15, q42 = l2 >> 4;
    const int m4 = fl >> 2, mt = fl & 3;
    const int fg = 8 * m4 + 4 * kk + mt;
    const int ch = 64 * m4 + 16 * mt + cl2;
    const uint4v d = *(const uint4v*)&sm.ep.v[ch * 40 + q42 * 8];
    *(uint4v*)(vf + (((size_t)(b * 64 + jt)) * 32 + fg) * 512 + l2 * 8) = d;
  }
}

// ---------------- kernel 2: flash attention, 64-q blocks, 16 waves, 2-ss batch ----------------
// R9: 2 supersteps per barrier (8 barriers total), P 4-buffer ring (128 KB), va dbuf
// (refill consumed 2 e-steps later -> L2 latency off critical path), kb 2-ahead prefetch.
// Phase A: wave (kk_a = w&7, ha = w>>3): 16-key half of group kk_a, 4 q-tiles, x2 ss.
// Phase B: wave (m4 = w&3, kp = w>>2): kk in {2kp,2kp+1} x 2 ss, 4 mt x 4 nt each.
__global__ __launch_bounds__(1024, 4) void attn_kernel(
    const unsigned short* __restrict__ qT, const unsigned short* __restrict__ kT,
    const unsigned short* __restrict__ vf, const float* __restrict__ x,
    const float* __restrict__ gamma_p, float* __restrict__ out)
{
  __shared__ union __align__(16) {
    unsigned short P[4][8][4][2][64][4];  // [buf][kk][nt][half][lane][j]  128 KB ring
    float OmA[2][4][16][64][4];           // [j: kp2/kp3][m4][mt*4+nt][lane][r] 128 KB
                                          // (OmA[0] reused as OmB for kp1's sum)
  } sm;
  __shared__ float l_lds[16][4][64];      // [wave][nt][lane] partial l   16 KB
  __shared__ float l2[4][4][64];          // [part][nt][lane] stage-1 l    4 KB
  __shared__ __align__(16) unsigned short qls[4 * 64 * 8];  // Q B-frags   4 KB

  const int t = threadIdx.x;
  const int w = t >> 6, lane = t & 63, cl = lane & 15, q4 = lane >> 4;
  const int kk_a = w & 7, ha = w >> 3;    // phase A role
  const int m4 = w & 3, kp = w >> 2;      // phase B role
  const int blk = blockIdx.x;
  const int b  = (blk & 7) >> 1;                          // matches qkv affinity
  const int it = ((blk >> 3) << 1) + (blk & 1);           // 0..63
  const int i0 = it * 64;

  // stage Q frags into LDS (one-time)
  if (t < 256) {
    const int nt = t >> 6, lq = t & 63, clq = lq & 15, q4q = lq >> 4;
    *(uint4v*)&qls[t * 8] =
        *(const uint4v*)(qT + ((size_t)b * LL + i0 + 16 * nt + clq) * DD + q4q * 8);
  }

  const f32x4 zero = {0.f, 0.f, 0.f, 0.f};
  f32x4 O[4][4];                          // [mt][nt]: ch 64*m4+16*mt, q 16*nt
  #pragma unroll
  for (int mt = 0; mt < 4; ++mt)
    #pragma unroll
    for (int nt = 0; nt < 4; ++nt) O[mt][nt] = zero;
  float l_r[4] = {0.f, 0.f, 0.f, 0.f};

  // phase A source: kT rows 32*kk_a + 16*ha + cl, sigma-permuted storage
  const unsigned short* kbase =
      kT + ((size_t)b * LL + 32 * kk_a + 16 * ha + cl) * DD + q4 * 8;
  // phase B source: frag g = ss*8 + kk -> base ((g>>1)*32 + 8*m4 + 4*(g&1))*512
  const unsigned short* vroot = vf + ((size_t)(b * 64)) * 32 * 512 + lane * 8;

  short8 kb[2];                           // kb[j] holds keys of superstep ss0+j
  kb[0] = *(const short8*)kbase;
  kb[1] = *(const short8*)(kbase + (size_t)256 * DD);

  short8 va[2][4];                        // double-buffered [slot][mt]
  #pragma unroll
  for (int e = 0; e < 2; ++e) {
    const int g = 2 * kp + e;             // ss=0
    const size_t base = ((size_t)(g >> 1) * 32 + 8 * m4 + 4 * (g & 1)) * 512;
    #pragma unroll
    for (int mt = 0; mt < 4; ++mt)
      va[e][mt] = *(const short8*)(vroot + base + mt * 512);
  }
  __syncthreads();   // qls visible

  for (int it2 = 0; it2 < 8; ++it2) {
    const int ss0 = 2 * it2;
    const int b0 = ss0 & 3, b1 = b0 + 1;  // P ring slots for ss0, ss0+1

    // ---- phase A, superstep ss0 ----
    f32x4 s0[4];
    __builtin_amdgcn_s_setprio(1);
    #pragma unroll
    for (int nt = 0; nt < 4; ++nt)
      s0[nt] = __builtin_amdgcn_mfma_f32_16x16x32_bf16(
          kb[0], *(const short8*)&qls[(nt * 64 + lane) * 8], zero, 0, 0, 0);
    __builtin_amdgcn_s_setprio(0);
    kb[0] = *(const short8*)(kbase + (size_t)(((ss0 + 2) & 15) * 256) * DD);
    #pragma unroll
    for (int nt = 0; nt < 4; ++nt) {
      const float e0 = fast_exp2(s0[nt][0]);
      const float e1 = fast_exp2(s0[nt][1]);
      const float e2 = fast_exp2(s0[nt][2]);
      const float e3 = fast_exp2(s0[nt][3]);
      uint2v uv;
      uv.x = __builtin_amdgcn_perm(__float_as_uint(e1), __float_as_uint(e0), 0x07060302);
      uv.y = __builtin_amdgcn_perm(__float_as_uint(e3), __float_as_uint(e2), 0x07060302);
      *(uint2v*)&sm.P[b0][kk_a][nt][ha][lane][0] = uv;    // 8B/lane: conflict-free
      l_r[nt] += (e0 + e1) + (e2 + e3);                   // per-lane partial
    }

    // ---- phase A, superstep ss0+1 ----
    f32x4 s1[4];
    __builtin_amdgcn_s_setprio(1);
    #pragma unroll
    for (int nt = 0; nt < 4; ++nt)
      s1[nt] = __builtin_amdgcn_mfma_f32_16x16x32_bf16(
          kb[1], *(const short8*)&qls[(nt * 64 + lane) * 8], zero, 0, 0, 0);
    __builtin_amdgcn_s_setprio(0);
    kb[1] = *(const short8*)(kbase + (size_t)(((ss0 + 3) & 15) * 256) * DD);
    #pragma unroll
    for (int nt = 0; nt < 4; ++nt) {
      const float e0 = fast_exp2(s1[nt][0]);
      const float e1 = fast_exp2(s1[nt][1]);
      const float e2 = fast_exp2(s1[nt][2]);
      const float e3 = fast_exp2(s1[nt][3]);
      uint2v uv;
      uv.x = __builtin_amdgcn_perm(__float_as_uint(e1), __float_as_uint(e0), 0x07060302);
      uv.y = __builtin_amdgcn_perm(__float_as_uint(e3), __float_as_uint(e2), 0x07060302);
      *(uint2v*)&sm.P[b1][kk_a][nt][ha][lane][0] = uv;
      l_r[nt] += (e0 + e1) + (e2 + e3);
    }
    BARRIER();

    // ---- phase B: 4 e-steps = (ss0,kk0),(ss0,kk1),(ss0+1,kk0),(ss0+1,kk1) ----
    #pragma unroll
    for (int e = 0; e < 4; ++e) {
      const int bufe = (e < 2) ? b0 : b1;
      const int kk = 2 * kp + (e & 1);
      short8 pb[4];
      #pragma unroll
      for (int nt = 0; nt < 4; ++nt) {
        union { short8 s8; uint2v h[2]; } pbu;
        pbu.h[0] = *(const uint2v*)&sm.P[bufe][kk][nt][0][lane][0];  // conflict-free b64
        pbu.h[1] = *(const uint2v*)&sm.P[bufe][kk][nt][1][lane][0];
        pb[nt] = pbu.s8;
      }
      __builtin_amdgcn_s_setprio(1);
      #pragma unroll
      for (int mt = 0; mt < 4; ++mt)
        #pragma unroll
        for (int nt = 0; nt < 4; ++nt)
          O[mt][nt] = __builtin_amdgcn_mfma_f32_16x16x32_bf16(va[e & 1][mt], pb[nt],
                                                              O[mt][nt], 0, 0, 0);
      __builtin_amdgcn_s_setprio(0);
      // refill slot e&1, consumed 2 e-steps later:
      // e<2 -> (ss0+1, 2kp+(e&1)); e>=2 -> (ss0+2, 2kp+(e&1))
      const int nss = (e < 2) ? (ss0 + 1) : ((ss0 + 2) & 15);
      const int g = nss * 8 + 2 * kp + (e & 1);
      const size_t base = ((size_t)(g >> 1) * 32 + 8 * m4 + 4 * (g & 1)) * 512;
      #pragma unroll
      for (int mt = 0; mt < 4; ++mt)
        va[e & 1][mt] = *(const short8*)(vroot + base + mt * 512);
    }
  }

  // ---- epilogue ----
  #pragma unroll
  for (int nt = 0; nt < 4; ++nt)
    l_lds[w][nt][lane] = l_r[nt];
  BARRIER();   // all P reads done (OmA may overwrite) + l_lds visible

  // stage-1 l reduce: wave w sums 4 of 16 slices for one nt
  {
    const int ntp = w >> 2, part = w & 3;
    float sl = l_lds[part * 4 + 0][ntp][lane] + l_lds[part * 4 + 1][ntp][lane]
             + l_lds[part * 4 + 2][ntp][lane] + l_lds[part * 4 + 3][ntp][lane];
    l2[part][ntp][lane] = sl;
  }
  if (kp >= 2) {   // kp2 -> OmA[0], kp3 -> OmA[1]
    #pragma unroll
    for (int mt = 0; mt < 4; ++mt)
      #pragma unroll
      for (int nt = 0; nt < 4; ++nt)
        *(f32x4*)&sm.OmA[kp - 2][m4][mt * 4 + nt][lane][0] = O[mt][nt];
  }
  BARRIER();
  if (kp < 2) {    // kp0 += kp2's, kp1 += kp3's
    #pragma unroll
    for (int mt = 0; mt < 4; ++mt)
      #pragma unroll
      for (int nt = 0; nt < 4; ++nt)
        O[mt][nt] += *(const f32x4*)&sm.OmA[kp][m4][mt * 4 + nt][lane][0];
  }
  BARRIER();
  if (kp == 1) {   // store kp1+kp3 sum into OmA[0] (OmB)
    #pragma unroll
    for (int mt = 0; mt < 4; ++mt)
      #pragma unroll
      for (int nt = 0; nt < 4; ++nt)
        *(f32x4*)&sm.OmA[0][m4][mt * 4 + nt][lane][0] = O[mt][nt];
  }
  BARRIER();
  if (kp == 0) {
    const float gam = gamma_p[0];
    float inv_l[4];
    #pragma unroll
    for (int nt = 0; nt < 4; ++nt) {
      float s = 0.f;
      #pragma unroll
      for (int part = 0; part < 4; ++part)
        #pragma unroll
        for (int g = 0; g < 4; ++g)
          s += l2[part][nt][g * 16 + cl];
      inv_l[nt] = 1.0f / s;
    }
    #pragma unroll
    for (int mt = 0; mt < 4; ++mt) {
      #pragma unroll
      for (int nt = 0; nt < 4; ++nt) {
        const f32x4 om = *(const f32x4*)&sm.OmA[0][m4][mt * 4 + nt][lane][0];
        #pragma unroll
        for (int r = 0; r < 4; ++r) {
          const int ch = 64 * m4 + 16 * mt + 4 * q4 + r;
          const int i  = i0 + 16 * nt + cl;
          const size_t idx = ((size_t)b * CC + ch) * LL + i;
          out[idx] = gam * (O[mt][nt][r] + om[r]) * inv_l[nt] + x[idx];
        }
      }
    }
  }
}

extern "C" void kernel_launch(void* const* d_in, const int* in_sizes, int n_in,
                              void* d_out, int out_size, void* d_ws, size_t ws_size,
                              hipStream_t stream) {
  const float* x     = (const float*)d_in[0];
  const float* Wq    = (const float*)d_in[1];
  const float* bq    = (const float*)d_in[2];
  const float* Wk    = (const float*)d_in[3];
  const float* bk    = (const float*)d_in[4];
  const float* Wv    = (const float*)d_in[5];
  const float* bv    = (const float*)d_in[6];
  const float* gamma = (const float*)d_in[7];
  float* out = (float*)d_out;

  // ws: qT (1MB, log2e-scaled) | kT (1MB, sigma rows) | vf (8MB, fragment-linear)
  unsigned short* qT = (unsigned short*)d_ws;
  unsigned short* kT = qT + (size_t)BB * LL * DD;
  unsigned short* vf = kT + (size_t)BB * LL * DD;
  // wf (160KB) lives in d_out; consumed by qkv, then attn overwrites d_out
  unsigned short* wf = (unsigned short*)d_out;

  wprep_kernel<<<40, 256, 0, stream>>>(Wq, Wk, Wv, wf);
  qkv_kernel<<<512, 512, 0, stream>>>(x, wf, bq, bk, bv, qT, kT, vf);
  attn_kernel<<<256, 1024, 0, stream>>>(qT, kT, vf, x, gamma, out);
}

// Round 4
// 133.435 us; speedup vs baseline: 1.4676x; 1.4676x over previous
//
#include <hip/hip_runtime.h>
#include <math.h>

#define BB 4
#define CC 256
#define LL 4096
#define DD 32   // q/k channels
#define LOG2E 1.44269504088896f

typedef __attribute__((ext_vector_type(8))) short short8;   // 8 bf16 (4 VGPRs)
typedef __attribute__((ext_vector_type(4))) short short4v;
typedef __attribute__((ext_vector_type(4))) float f32x4;
typedef __attribute__((ext_vector_type(4))) unsigned int uint4v;
typedef __attribute__((ext_vector_type(2))) unsigned int uint2v;

// raw workgroup barrier: waits LDS ops only — global prefetches stay in flight
#define BARRIER() asm volatile("s_waitcnt lgkmcnt(0)\n\ts_barrier" ::: "memory")

__device__ inline unsigned short f2bf(float f) {
  union { float f; unsigned u; } v; v.f = f;
  unsigned r = v.u + 0x7fffu + ((v.u >> 16) & 1u);  // RNE
  return (unsigned short)(r >> 16);
}

__device__ inline float fast_exp2(float x) {
#if __has_builtin(__builtin_amdgcn_exp2f)
  return __builtin_amdgcn_exp2f(x);
#else
  return exp2f(x);
#endif
}

// natural key p -> kT storage row within its 32-key group (P C-layout == PV B-layout)
__device__ __host__ inline int sigma32(int p) {
  const int q4 = (p >> 3) & 3, u = p & 7;
  return 16 * (u >> 2) + 4 * q4 + (u & 3);
}

// ---------------- kernel 0: W -> bf16 MFMA-fragment-linear layout ----------------
// wf[ot(20)][ks(8)][lane(64)][8]; Wq rows pre-scaled by log2(e).
__global__ __launch_bounds__(256) void wprep_kernel(
    const float* __restrict__ Wq, const float* __restrict__ Wk, const float* __restrict__ Wv,
    unsigned short* __restrict__ wf)
{
  const int t = threadIdx.x;
  const int ot = blockIdx.x >> 1;           // 0..19
  const int rep = blockIdx.x & 1;
  const int lane = t & 63, cl = lane & 15, q4 = lane >> 4;
  const int ks = (t >> 6) + 4 * rep;        // 0..7
  const int o = ot * 16 + cl;
  const int c = ks * 32 + q4 * 8;
  const float* src = (o < 32) ? (Wq + o * CC) : (o < 64) ? (Wk + (o - 32) * CC)
                                              : (Wv + (o - 64) * CC);
  const float sc = (o < 32) ? LOG2E : 1.0f;
  unsigned short p[8];
  #pragma unroll
  for (int j = 0; j < 8; ++j) p[j] = f2bf(src[c + j] * sc);
  uint4v u;
  u.x = (unsigned)p[0] | ((unsigned)p[1] << 16);
  u.y = (unsigned)p[2] | ((unsigned)p[3] << 16);
  u.z = (unsigned)p[4] | ((unsigned)p[5] << 16);
  u.w = (unsigned)p[6] | ((unsigned)p[7] << 16);
  *(uint4v*)(wf + ((size_t)(ot * 8 + ks) * 64 + lane) * 8) = u;
}

// ---------------- kernel 1: fused transpose + QKV projection (R6-proven) ----------------
// grid 512 = (b, it 32-i tile) XCD-affine; 512 thr = 8 waves (wi 16-i, wo 5-ot).
__global__ __launch_bounds__(512, 4) void qkv_kernel(
    const float* __restrict__ x, const unsigned short* __restrict__ wf,
    const float* __restrict__ bq, const float* __restrict__ bk, const float* __restrict__ bv,
    unsigned short* __restrict__ qT, unsigned short* __restrict__ kT,
    unsigned short* __restrict__ vf)
{
  __shared__ union {
    float xl[32 * 261];                                   // [i][c] odd stride
    struct {
      unsigned short qk[32 * 72];                         // [i][o 0..63]
      __align__(16) unsigned short v[256 * 40];           // [ch][key 0..31] pad-40
    } ep;
  } sm;

  const int t = threadIdx.x;
  const int lane = t & 63, cl = lane & 15, q4 = lane >> 4;
  const int blk = blockIdx.x;
  const int b  = (blk & 7) >> 1;                          // XCD-batch affinity
  const int it = ((blk >> 3) << 1) + (blk & 1);           // 0..127
  const int i0 = it * 32;

  // ---- stage x: coalesced 128B rows -> LDS transposed ----
  {
    const int ln8 = t & 7;
    #pragma unroll
    for (int p = 0; p < 4; ++p) {
      const int c = (t >> 3) + 64 * p;
      const f32x4 v = *(const f32x4*)(x + ((size_t)(b * CC + c)) * LL + i0 + ln8 * 4);
      #pragma unroll
      for (int k = 0; k < 4; ++k) sm.xl[(ln8 * 4 + k) * 261 + c] = v[k];
    }
  }
  __syncthreads();

  // ---- GEMM: wave (wi,wo): 80 o-rows x 16 i x 256 c ----
  const int wi = (t >> 6) & 1, wo = t >> 7;
  const f32x4 zero = {0.f, 0.f, 0.f, 0.f};
  f32x4 acc[5];
  #pragma unroll
  for (int u = 0; u < 5; ++u) acc[u] = zero;

  for (int ks = 0; ks < 8; ++ks) {
    unsigned short p[8];
    #pragma unroll
    for (int j = 0; j < 8; ++j)
      p[j] = f2bf(sm.xl[(16 * wi + cl) * 261 + ks * 32 + q4 * 8 + j]);
    union { short8 s; uint4v u; } bfr;
    bfr.u.x = (unsigned)p[0] | ((unsigned)p[1] << 16);
    bfr.u.y = (unsigned)p[2] | ((unsigned)p[3] << 16);
    bfr.u.z = (unsigned)p[4] | ((unsigned)p[5] << 16);
    bfr.u.w = (unsigned)p[6] | ((unsigned)p[7] << 16);
    #pragma unroll
    for (int u = 0; u < 5; ++u) {
      const short8 a = *(const short8*)(wf + ((size_t)((wo * 5 + u) * 8 + ks) * 64 + lane) * 8);
      acc[u] = __builtin_amdgcn_mfma_f32_16x16x32_bf16(a, bfr.s, acc[u], 0, 0, 0);
    }
  }
  __syncthreads();   // xl dead; alias as ep

  // ---- stage outputs ----
  #pragma unroll
  for (int u = 0; u < 5; ++u) {
    const int g = wo * 5 + u;
    if (g < 4) {     // q (g<2) / k
      short4v pk;
      #pragma unroll
      for (int r = 0; r < 4; ++r) {
        const int o = 16 * g + 4 * q4 + r;
        const float v = acc[u][r] + ((o < 32) ? bq[o] * LOG2E : bk[o - 32]);
        pk[r] = (short)f2bf(v);
      }
      *(short4v*)&sm.ep.qk[(16 * wi + cl) * 72 + 16 * g + 4 * q4] = pk;
    } else {
      #pragma unroll
      for (int r = 0; r < 4; ++r) {
        const int ch = 16 * (g - 4) + 4 * q4 + r;
        sm.ep.v[ch * 40 + 16 * wi + cl] = f2bf(acc[u][r] + bv[ch]);
      }
    }
  }
  __syncthreads();

  // ---- coalesced stores ----
  if (t < 64) {
    const int i = t >> 1, which = t & 1;
    const int gi = i0 + i;
    const unsigned short* srcp = &sm.ep.qk[i * 72 + which * 32];
    uint4v d0 = *(const uint4v*)(srcp + 0);
    uint4v d1 = *(const uint4v*)(srcp + 8);
    uint4v d2 = *(const uint4v*)(srcp + 16);
    uint4v d3 = *(const uint4v*)(srcp + 24);
    unsigned short* dst;
    if (which == 0) {
      dst = qT + ((size_t)b * LL + gi) * DD;
    } else {
      const int row = (gi & ~31) + sigma32(gi & 31);
      dst = kT + ((size_t)b * LL + row) * DD;
    }
    *(uint4v*)dst = d0; *(uint4v*)(dst + 8) = d1;
    *(uint4v*)(dst + 16) = d2; *(uint4v*)(dst + 24) = d3;
  }
  // vf: this block covers kk = it&1 of jt = it>>1: 16 frags x 1KB
  const int kk = it & 1, jt = it >> 1;
  #pragma unroll
  for (int rep = 0; rep < 2; ++rep) {
    const int slot = t + 512 * rep;
    const int fl = slot >> 6, l2 = slot & 63;
    const int cl2 = l2 & 15, q42 = l2 >> 4;
    const int m4 = fl >> 2, mt = fl & 3;
    const int fg = 8 * m4 + 4 * kk + mt;
    const int ch = 64 * m4 + 16 * mt + cl2;
    const uint4v d = *(const uint4v*)&sm.ep.v[ch * 40 + q42 * 8];
    *(uint4v*)(vf + (((size_t)(b * 64 + jt)) * 32 + fg) * 512 + l2 * 8) = d;
  }
}

// ---------------- kernel 2: flash attention, 64-q blocks, 16 waves, 2-ss batch ----------------
// R10: R9 schedule (2 ss/barrier, 4-slot P ring, va dbuf 2-step slack) with the register
// budget FIXED: phase B waves own 32 ch (m8 = w&7) x half the kk-groups (kp = w>>3),
// so O is [2][4] = 32 VGPRs (was 64). Est total ~105 < 128 cap at 4 waves/SIMD -> no spill.
// Phase A unchanged: wave (kk_a = w&7, ha = w>>3): 16-key half, 4 q-tiles, x2 ss.
__global__ __launch_bounds__(1024, 4) void attn_kernel(
    const unsigned short* __restrict__ qT, const unsigned short* __restrict__ kT,
    const unsigned short* __restrict__ vf, const float* __restrict__ x,
    const float* __restrict__ gamma_p, float* __restrict__ out)
{
  __shared__ union __align__(16) {
    unsigned short P[4][8][4][2][64][4];  // [buf][kk][nt][half][lane][j]  128 KB ring
    float Om[8][8][64][4];                // [m8][j*4+nt][lane][r]          64 KB
  } sm;
  __shared__ float l_lds[16][4][64];      // [wave][nt][lane] partial l     16 KB
  __shared__ float l2s[4][4][64];         // [part][nt][lane] stage-1 l      4 KB
  __shared__ __align__(16) unsigned short qls[4 * 64 * 8];  // Q B-frags     4 KB

  const int t = threadIdx.x;
  const int w = t >> 6, lane = t & 63, cl = lane & 15, q4 = lane >> 4;
  const int kk_a = w & 7, ha = w >> 3;    // phase A role
  const int m8 = w & 7, kp = w >> 3;      // phase B role: ch 32*m8, kk 4*kp..4*kp+3
  const int m4 = m8 >> 1, mtA = 2 * (m8 & 1);
  const int blk = blockIdx.x;
  const int b  = (blk & 7) >> 1;                          // matches qkv affinity
  const int it = ((blk >> 3) << 1) + (blk & 1);           // 0..63
  const int i0 = it * 64;

  // stage Q frags into LDS (one-time)
  if (t < 256) {
    const int nt = t >> 6, lq = t & 63, clq = lq & 15, q4q = lq >> 4;
    *(uint4v*)&qls[t * 8] =
        *(const uint4v*)(qT + ((size_t)b * LL + i0 + 16 * nt + clq) * DD + q4q * 8);
  }

  const f32x4 zero = {0.f, 0.f, 0.f, 0.f};
  f32x4 O[2][4];                          // [j][nt]: ch 32*m8+16*j, q 16*nt
  #pragma unroll
  for (int j = 0; j < 2; ++j)
    #pragma unroll
    for (int nt = 0; nt < 4; ++nt) O[j][nt] = zero;
  float l_r[4] = {0.f, 0.f, 0.f, 0.f};

  // phase A source: kT rows 32*kk_a + 16*ha + cl, sigma-permuted storage
  const unsigned short* kbase =
      kT + ((size_t)b * LL + 32 * kk_a + 16 * ha + cl) * DD + q4 * 8;
  // phase B source: frag g = ss*8 + kk -> base ((g>>1)*32 + 8*m4 + 4*(g&1) + mtA)*512
  const unsigned short* vroot = vf + ((size_t)(b * 64)) * 32 * 512 + lane * 8;

  short8 kb[2];                           // kb[j] holds keys of superstep ss0+j
  kb[0] = *(const short8*)kbase;
  kb[1] = *(const short8*)(kbase + (size_t)256 * DD);

  short8 va[2][2];                        // [slot ee&1][j]
  #pragma unroll
  for (int e = 0; e < 2; ++e) {
    const int g = 4 * kp + e;             // ss=0, ee=e
    const size_t base = ((size_t)(g >> 1) * 32 + 8 * m4 + 4 * (g & 1) + mtA) * 512;
    #pragma unroll
    for (int j = 0; j < 2; ++j)
      va[e][j] = *(const short8*)(vroot + base + j * 512);
  }
  __syncthreads();   // qls visible

  for (int it2 = 0; it2 < 8; ++it2) {
    const int ss0 = 2 * it2;
    const int b0 = ss0 & 3;               // P ring slots b0, b0+1

    // ---- phase A, superstep ss0 ----
    {
      f32x4 s[4];
      __builtin_amdgcn_s_setprio(1);
      #pragma unroll
      for (int nt = 0; nt < 4; ++nt)
        s[nt] = __builtin_amdgcn_mfma_f32_16x16x32_bf16(
            kb[0], *(const short8*)&qls[(nt * 64 + lane) * 8], zero, 0, 0, 0);
      __builtin_amdgcn_s_setprio(0);
      kb[0] = *(const short8*)(kbase + (size_t)(((ss0 + 2) & 15) * 256) * DD);
      #pragma unroll
      for (int nt = 0; nt < 4; ++nt) {
        const float e0 = fast_exp2(s[nt][0]);
        const float e1 = fast_exp2(s[nt][1]);
        const float e2 = fast_exp2(s[nt][2]);
        const float e3 = fast_exp2(s[nt][3]);
        uint2v uv;
        uv.x = __builtin_amdgcn_perm(__float_as_uint(e1), __float_as_uint(e0), 0x07060302);
        uv.y = __builtin_amdgcn_perm(__float_as_uint(e3), __float_as_uint(e2), 0x07060302);
        *(uint2v*)&sm.P[b0][kk_a][nt][ha][lane][0] = uv;  // 8B/lane: conflict-free
        l_r[nt] += (e0 + e1) + (e2 + e3);                 // per-lane partial
      }
    }

    // ---- phase A, superstep ss0+1 ----
    {
      f32x4 s[4];
      __builtin_amdgcn_s_setprio(1);
      #pragma unroll
      for (int nt = 0; nt < 4; ++nt)
        s[nt] = __builtin_amdgcn_mfma_f32_16x16x32_bf16(
            kb[1], *(const short8*)&qls[(nt * 64 + lane) * 8], zero, 0, 0, 0);
      __builtin_amdgcn_s_setprio(0);
      kb[1] = *(const short8*)(kbase + (size_t)(((ss0 + 3) & 15) * 256) * DD);
      #pragma unroll
      for (int nt = 0; nt < 4; ++nt) {
        const float e0 = fast_exp2(s[nt][0]);
        const float e1 = fast_exp2(s[nt][1]);
        const float e2 = fast_exp2(s[nt][2]);
        const float e3 = fast_exp2(s[nt][3]);
        uint2v uv;
        uv.x = __builtin_amdgcn_perm(__float_as_uint(e1), __float_as_uint(e0), 0x07060302);
        uv.y = __builtin_amdgcn_perm(__float_as_uint(e3), __float_as_uint(e2), 0x07060302);
        *(uint2v*)&sm.P[b0 + 1][kk_a][nt][ha][lane][0] = uv;
        l_r[nt] += (e0 + e1) + (e2 + e3);
      }
    }
    BARRIER();

    // ---- phase B: 8 e-steps = (ss0|ss0+1) x kk = 4kp..4kp+3 ----
    #pragma unroll
    for (int ee = 0; ee < 8; ++ee) {
      const int e = ee & 3;
      const int kk = 4 * kp + e;
      const int buf = b0 + (ee >> 2);
      short8 pb[4];
      #pragma unroll
      for (int nt = 0; nt < 4; ++nt) {
        union { short8 s8; uint2v h[2]; } pbu;
        pbu.h[0] = *(const uint2v*)&sm.P[buf][kk][nt][0][lane][0];  // conflict-free b64
        pbu.h[1] = *(const uint2v*)&sm.P[buf][kk][nt][1][lane][0];
        pb[nt] = pbu.s8;
      }
      __builtin_amdgcn_s_setprio(1);
      #pragma unroll
      for (int j = 0; j < 2; ++j)
        #pragma unroll
        for (int nt = 0; nt < 4; ++nt)
          O[j][nt] = __builtin_amdgcn_mfma_f32_16x16x32_bf16(va[ee & 1][j], pb[nt],
                                                             O[j][nt], 0, 0, 0);
      __builtin_amdgcn_s_setprio(0);
      // refill slot ee&1, consumed at e-step ee+2 (~full e-step of slack > L2 latency)
      const int nee = ee + 2;
      const int nss = (ss0 + (nee >> 2)) & 15;
      const int g = nss * 8 + 4 * kp + (nee & 3);
      const size_t base = ((size_t)(g >> 1) * 32 + 8 * m4 + 4 * (g & 1) + mtA) * 512;
      #pragma unroll
      for (int j = 0; j < 2; ++j)
        va[ee & 1][j] = *(const short8*)(vroot + base + j * 512);
    }
  }

  // ---- epilogue ----
  #pragma unroll
  for (int nt = 0; nt < 4; ++nt)
    l_lds[w][nt][lane] = l_r[nt];
  BARRIER();   // all P reads done (Om may overwrite P[0..1] region) + l_lds visible

  // stage-1 l reduce: wave w sums 4 of 16 slices for one nt
  {
    const int ntp = w >> 2, part = w & 3;
    float sl = l_lds[part * 4 + 0][ntp][lane] + l_lds[part * 4 + 1][ntp][lane]
             + l_lds[part * 4 + 2][ntp][lane] + l_lds[part * 4 + 3][ntp][lane];
    l2s[part][ntp][lane] = sl;
  }
  if (kp == 1) {   // store partial O -> Om
    #pragma unroll
    for (int j = 0; j < 2; ++j)
      #pragma unroll
      for (int nt = 0; nt < 4; ++nt)
        *(f32x4*)&sm.Om[m8][j * 4 + nt][lane][0] = O[j][nt];
  }
  BARRIER();
  if (kp == 0) {
    const float gam = gamma_p[0];
    float inv_l[4];
    #pragma unroll
    for (int nt = 0; nt < 4; ++nt) {
      float s = 0.f;
      #pragma unroll
      for (int part = 0; part < 4; ++part)
        #pragma unroll
        for (int g = 0; g < 4; ++g)
          s += l2s[part][nt][g * 16 + cl];
      inv_l[nt] = 1.0f / s;
    }
    #pragma unroll
    for (int j = 0; j < 2; ++j) {
      #pragma unroll
      for (int nt = 0; nt < 4; ++nt) {
        const f32x4 om = *(const f32x4*)&sm.Om[m8][j * 4 + nt][lane][0];
        #pragma unroll
        for (int r = 0; r < 4; ++r) {
          const int ch = 32 * m8 + 16 * j + 4 * q4 + r;
          const int i  = i0 + 16 * nt + cl;
          const size_t idx = ((size_t)b * CC + ch) * LL + i;
          out[idx] = gam * (O[j][nt][r] + om[r]) * inv_l[nt] + x[idx];
        }
      }
    }
  }
}

extern "C" void kernel_launch(void* const* d_in, const int* in_sizes, int n_in,
                              void* d_out, int out_size, void* d_ws, size_t ws_size,
                              hipStream_t stream) {
  const float* x     = (const float*)d_in[0];
  const float* Wq    = (const float*)d_in[1];
  const float* bq    = (const float*)d_in[2];
  const float* Wk    = (const float*)d_in[3];
  const float* bk    = (const float*)d_in[4];
  const float* Wv    = (const float*)d_in[5];
  const float* bv    = (const float*)d_in[6];
  const float* gamma = (const float*)d_in[7];
  float* out = (float*)d_out;

  // ws: qT (1MB, log2e-scaled) | kT (1MB, sigma rows) | vf (8MB, fragment-linear)
  unsigned short* qT = (unsigned short*)d_ws;
  unsigned short* kT = qT + (size_t)BB * LL * DD;
  unsigned short* vf = kT + (size_t)BB * LL * DD;
  // wf (160KB) lives in d_out; consumed by qkv, then attn overwrites d_out
  unsigned short* wf = (unsigned short*)d_out;

  wprep_kernel<<<40, 256, 0, stream>>>(Wq, Wk, Wv, wf);
  qkv_kernel<<<512, 512, 0, stream>>>(x, wf, bq, bk, bv, qT, kT, vf);
  attn_kernel<<<256, 1024, 0, stream>>>(qT, kT, vf, x, gamma, out);
}

// Round 5
// 131.637 us; speedup vs baseline: 1.4876x; 1.0137x over previous
//
#include <hip/hip_runtime.h>
#include <math.h>

#define BB 4
#define CC 256
#define LL 4096
#define DD 32   // q/k channels
#define LOG2E 1.44269504088896f

typedef __attribute__((ext_vector_type(8))) short short8;   // 8 bf16 (4 VGPRs)
typedef __attribute__((ext_vector_type(4))) short short4v;
typedef __attribute__((ext_vector_type(4))) float f32x4;
typedef __attribute__((ext_vector_type(4))) unsigned int uint4v;
typedef __attribute__((ext_vector_type(2))) unsigned int uint2v;

// raw workgroup barrier: waits LDS ops only — global prefetches stay in flight
#define BARRIER() asm volatile("s_waitcnt lgkmcnt(0)\n\ts_barrier" ::: "memory")

__device__ inline unsigned short f2bf(float f) {
  union { float f; unsigned u; } v; v.f = f;
  unsigned r = v.u + 0x7fffu + ((v.u >> 16) & 1u);  // RNE
  return (unsigned short)(r >> 16);
}

__device__ inline float fast_exp2(float x) {
#if __has_builtin(__builtin_amdgcn_exp2f)
  return __builtin_amdgcn_exp2f(x);
#else
  return exp2f(x);
#endif
}

// natural key p -> kT storage row within its 32-key group (P C-layout == PV B-layout)
__device__ __host__ inline int sigma32(int p) {
  const int q4 = (p >> 3) & 3, u = p & 7;
  return 16 * (u >> 2) + 4 * q4 + (u & 3);
}

// ---------------- kernel 0: W -> bf16 MFMA-fragment-linear layout ----------------
// wf[ot(20)][ks(8)][lane(64)][8]; Wq rows pre-scaled by log2(e).
__global__ __launch_bounds__(256) void wprep_kernel(
    const float* __restrict__ Wq, const float* __restrict__ Wk, const float* __restrict__ Wv,
    unsigned short* __restrict__ wf)
{
  const int t = threadIdx.x;
  const int ot = blockIdx.x >> 1;           // 0..19
  const int rep = blockIdx.x & 1;
  const int lane = t & 63, cl = lane & 15, q4 = lane >> 4;
  const int ks = (t >> 6) + 4 * rep;        // 0..7
  const int o = ot * 16 + cl;
  const int c = ks * 32 + q4 * 8;
  const float* src = (o < 32) ? (Wq + o * CC) : (o < 64) ? (Wk + (o - 32) * CC)
                                              : (Wv + (o - 64) * CC);
  const float sc = (o < 32) ? LOG2E : 1.0f;
  unsigned short p[8];
  #pragma unroll
  for (int j = 0; j < 8; ++j) p[j] = f2bf(src[c + j] * sc);
  uint4v u;
  u.x = (unsigned)p[0] | ((unsigned)p[1] << 16);
  u.y = (unsigned)p[2] | ((unsigned)p[3] << 16);
  u.z = (unsigned)p[4] | ((unsigned)p[5] << 16);
  u.w = (unsigned)p[6] | ((unsigned)p[7] << 16);
  *(uint4v*)(wf + ((size_t)(ot * 8 + ks) * 64 + lane) * 8) = u;
}

// ---------------- kernel 1: fused transpose + QKV projection (R6-proven) ----------------
// grid 512 = (b, it 32-i tile) XCD-affine; 512 thr = 8 waves (wi 16-i, wo 5-ot).
__global__ __launch_bounds__(512, 4) void qkv_kernel(
    const float* __restrict__ x, const unsigned short* __restrict__ wf,
    const float* __restrict__ bq, const float* __restrict__ bk, const float* __restrict__ bv,
    unsigned short* __restrict__ qT, unsigned short* __restrict__ kT,
    unsigned short* __restrict__ vf)
{
  __shared__ union {
    float xl[32 * 261];                                   // [i][c] odd stride
    struct {
      unsigned short qk[32 * 72];                         // [i][o 0..63]
      __align__(16) unsigned short v[256 * 40];           // [ch][key 0..31] pad-40
    } ep;
  } sm;

  const int t = threadIdx.x;
  const int lane = t & 63, cl = lane & 15, q4 = lane >> 4;
  const int blk = blockIdx.x;
  const int b  = (blk & 7) >> 1;                          // XCD-batch affinity
  const int it = ((blk >> 3) << 1) + (blk & 1);           // 0..127
  const int i0 = it * 32;

  // ---- stage x: coalesced 128B rows -> LDS transposed ----
  {
    const int ln8 = t & 7;
    #pragma unroll
    for (int p = 0; p < 4; ++p) {
      const int c = (t >> 3) + 64 * p;
      const f32x4 v = *(const f32x4*)(x + ((size_t)(b * CC + c)) * LL + i0 + ln8 * 4);
      #pragma unroll
      for (int k = 0; k < 4; ++k) sm.xl[(ln8 * 4 + k) * 261 + c] = v[k];
    }
  }
  __syncthreads();

  // ---- GEMM: wave (wi,wo): 80 o-rows x 16 i x 256 c ----
  const int wi = (t >> 6) & 1, wo = t >> 7;
  const f32x4 zero = {0.f, 0.f, 0.f, 0.f};
  f32x4 acc[5];
  #pragma unroll
  for (int u = 0; u < 5; ++u) acc[u] = zero;

  for (int ks = 0; ks < 8; ++ks) {
    unsigned short p[8];
    #pragma unroll
    for (int j = 0; j < 8; ++j)
      p[j] = f2bf(sm.xl[(16 * wi + cl) * 261 + ks * 32 + q4 * 8 + j]);
    union { short8 s; uint4v u; } bfr;
    bfr.u.x = (unsigned)p[0] | ((unsigned)p[1] << 16);
    bfr.u.y = (unsigned)p[2] | ((unsigned)p[3] << 16);
    bfr.u.z = (unsigned)p[4] | ((unsigned)p[5] << 16);
    bfr.u.w = (unsigned)p[6] | ((unsigned)p[7] << 16);
    #pragma unroll
    for (int u = 0; u < 5; ++u) {
      const short8 a = *(const short8*)(wf + ((size_t)((wo * 5 + u) * 8 + ks) * 64 + lane) * 8);
      acc[u] = __builtin_amdgcn_mfma_f32_16x16x32_bf16(a, bfr.s, acc[u], 0, 0, 0);
    }
  }
  __syncthreads();   // xl dead; alias as ep

  // ---- stage outputs ----
  #pragma unroll
  for (int u = 0; u < 5; ++u) {
    const int g = wo * 5 + u;
    if (g < 4) {     // q (g<2) / k
      short4v pk;
      #pragma unroll
      for (int r = 0; r < 4; ++r) {
        const int o = 16 * g + 4 * q4 + r;
        const float v = acc[u][r] + ((o < 32) ? bq[o] * LOG2E : bk[o - 32]);
        pk[r] = (short)f2bf(v);
      }
      *(short4v*)&sm.ep.qk[(16 * wi + cl) * 72 + 16 * g + 4 * q4] = pk;
    } else {
      #pragma unroll
      for (int r = 0; r < 4; ++r) {
        const int ch = 16 * (g - 4) + 4 * q4 + r;
        sm.ep.v[ch * 40 + 16 * wi + cl] = f2bf(acc[u][r] + bv[ch]);
      }
    }
  }
  __syncthreads();

  // ---- coalesced stores ----
  if (t < 64) {
    const int i = t >> 1, which = t & 1;
    const int gi = i0 + i;
    const unsigned short* srcp = &sm.ep.qk[i * 72 + which * 32];
    uint4v d0 = *(const uint4v*)(srcp + 0);
    uint4v d1 = *(const uint4v*)(srcp + 8);
    uint4v d2 = *(const uint4v*)(srcp + 16);
    uint4v d3 = *(const uint4v*)(srcp + 24);
    unsigned short* dst;
    if (which == 0) {
      dst = qT + ((size_t)b * LL + gi) * DD;
    } else {
      const int row = (gi & ~31) + sigma32(gi & 31);
      dst = kT + ((size_t)b * LL + row) * DD;
    }
    *(uint4v*)dst = d0; *(uint4v*)(dst + 8) = d1;
    *(uint4v*)(dst + 16) = d2; *(uint4v*)(dst + 24) = d3;
  }
  // vf: this block covers kk = it&1 of jt = it>>1: 16 frags x 1KB
  const int kk = it & 1, jt = it >> 1;
  #pragma unroll
  for (int rep = 0; rep < 2; ++rep) {
    const int slot = t + 512 * rep;
    const int fl = slot >> 6, l2 = slot & 63;
    const int cl2 = l2 & 15, q42 = l2 >> 4;
    const int m4 = fl >> 2, mt = fl & 3;
    const int fg = 8 * m4 + 4 * kk + mt;
    const int ch = 64 * m4 + 16 * mt + cl2;
    const uint4v d = *(const uint4v*)&sm.ep.v[ch * 40 + q42 * 8];
    *(uint4v*)(vf + (((size_t)(b * 64 + jt)) * 32 + fg) * 512 + l2 * 8) = d;
  }
}

// ---------------- kernel 2: flash attention, producer/consumer wave split ----------------
// R11: 768 thr = 8 producer waves (QK^T+exp+pack -> P ring) + 4 consumer waves (PV).
// Per SIMD: 2P + 1C -> producer VALU overlaps consumer MFMA between the same barriers.
// Window = 256 keys, 16 windows, P ring depth 2. Producer pw: kk=pw, h=0..1, 4 nt
// (8 QK MFMA + 32 exp). Consumer mq = w-8: ch 64*mq..+63 over ALL keys (16 MFMA x 8
// e-steps/window); no cross-wave O combine. P stored [kk][nt][lane][16B] -> b128 ops.
__global__ __launch_bounds__(768, 3) void attn_kernel(
    const unsigned short* __restrict__ qT, const unsigned short* __restrict__ kT,
    const unsigned short* __restrict__ vf, const float* __restrict__ x,
    const float* __restrict__ gamma_p, float* __restrict__ out)
{
  __shared__ __align__(16) unsigned short P[2][8][4][64][8];  // [buf][kk][nt][lane][8] 64 KB
  __shared__ float l_lds[8][4][64];                           // [pw][nt][lane]          8 KB

  const int t = threadIdx.x;
  const int w = t >> 6, lane = t & 63, cl = lane & 15, q4 = lane >> 4;
  const int blk = blockIdx.x;
  const int b  = (blk & 7) >> 1;                          // matches qkv affinity
  const int it = ((blk >> 3) << 1) + (blk & 1);           // 0..63
  const int i0 = it * 64;
  const f32x4 zero = {0.f, 0.f, 0.f, 0.f};

  if (w < 8) {
    // ================= producer =================
    const int pw = w;
    short8 qa[4];
    #pragma unroll
    for (int nt = 0; nt < 4; ++nt)
      qa[nt] = *(const short8*)(qT + ((size_t)b * LL + i0 + 16 * nt + cl) * DD + q4 * 8);
    const unsigned short* kbase =
        kT + ((size_t)b * LL + 32 * pw + cl) * DD + q4 * 8;
    short8 kb0 = *(const short8*)kbase;                       // ss0, h=0
    short8 kb1 = *(const short8*)(kbase + (size_t)16 * DD);   // ss0, h=1
    float l_r[4] = {0.f, 0.f, 0.f, 0.f};

    auto produce = [&](int ss, int buf) {
      f32x4 s0[4], s1[4];
      #pragma unroll
      for (int nt = 0; nt < 4; ++nt)
        s0[nt] = __builtin_amdgcn_mfma_f32_16x16x32_bf16(kb0, qa[nt], zero, 0, 0, 0);
      #pragma unroll
      for (int nt = 0; nt < 4; ++nt)
        s1[nt] = __builtin_amdgcn_mfma_f32_16x16x32_bf16(kb1, qa[nt], zero, 0, 0, 0);
      // prefetch next window's kb (global, in flight across barrier)
      const int nss = (ss + 1) & 15;
      kb0 = *(const short8*)(kbase + (size_t)(nss * 256) * DD);
      kb1 = *(const short8*)(kbase + (size_t)(nss * 256 + 16) * DD);
      #pragma unroll
      for (int nt = 0; nt < 4; ++nt) {
        const float a0 = fast_exp2(s0[nt][0]);
        const float a1 = fast_exp2(s0[nt][1]);
        const float a2 = fast_exp2(s0[nt][2]);
        const float a3 = fast_exp2(s0[nt][3]);
        const float b0 = fast_exp2(s1[nt][0]);
        const float b1 = fast_exp2(s1[nt][1]);
        const float b2 = fast_exp2(s1[nt][2]);
        const float b3 = fast_exp2(s1[nt][3]);
        uint4v u;
        u.x = __builtin_amdgcn_perm(__float_as_uint(a1), __float_as_uint(a0), 0x07060302);
        u.y = __builtin_amdgcn_perm(__float_as_uint(a3), __float_as_uint(a2), 0x07060302);
        u.z = __builtin_amdgcn_perm(__float_as_uint(b1), __float_as_uint(b0), 0x07060302);
        u.w = __builtin_amdgcn_perm(__float_as_uint(b3), __float_as_uint(b2), 0x07060302);
        *(uint4v*)&P[buf][pw][nt][lane][0] = u;   // b128, lane-contiguous: conflict-free
        l_r[nt] += ((a0 + a1) + (a2 + a3)) + ((b0 + b1) + (b2 + b3));
      }
    };

    produce(0, 0);
    __syncthreads();   // P(0) ready
    for (int i = 0; i < 16; ++i) {
      if (i < 15) produce(i + 1, (i + 1) & 1);
      BARRIER();
    }
    #pragma unroll
    for (int nt = 0; nt < 4; ++nt)
      l_lds[pw][nt][lane] = l_r[nt];
    BARRIER();
    // producers done
  } else {
    // ================= consumer =================
    const int mq = w - 8;   // 0..3: ch 64*mq .. +63
    const unsigned short* vroot = vf + ((size_t)(b * 64)) * 32 * 512 + lane * 8;
    f32x4 O[4][4];          // [j][nt]: ch 64*mq+16*j, q 16*nt
    #pragma unroll
    for (int j = 0; j < 4; ++j)
      #pragma unroll
      for (int nt = 0; nt < 4; ++nt) O[j][nt] = zero;

    short8 va[2][4];        // [slot g&1][j]; frag g = 8*ss + kk (consumption order)
    #pragma unroll
    for (int s = 0; s < 2; ++s) {
      const int g = s;
      const size_t base = ((size_t)(g >> 1) * 32 + 8 * mq + 4 * (g & 1)) * 512;
      #pragma unroll
      for (int j = 0; j < 4; ++j)
        va[s][j] = *(const short8*)(vroot + base + j * 512);
    }
    __syncthreads();   // P(0) ready

    for (int i = 0; i < 16; ++i) {
      const int buf = i & 1;
      short8 pb[2][4];     // double-buffered P fragments
      #pragma unroll
      for (int nt = 0; nt < 4; ++nt)
        pb[0][nt] = *(const short8*)&P[buf][0][nt][lane][0];   // kk=0 preload
      #pragma unroll
      for (int e = 0; e < 8; ++e) {
        const int cs = e & 1;
        if (e < 7) {
          #pragma unroll
          for (int nt = 0; nt < 4; ++nt)
            pb[cs ^ 1][nt] = *(const short8*)&P[buf][e + 1][nt][lane][0];
        }
        __builtin_amdgcn_s_setprio(1);
        #pragma unroll
        for (int j = 0; j < 4; ++j)
          #pragma unroll
          for (int nt = 0; nt < 4; ++nt)
            O[j][nt] = __builtin_amdgcn_mfma_f32_16x16x32_bf16(va[e & 1][j], pb[cs][nt],
                                                               O[j][nt], 0, 0, 0);
        __builtin_amdgcn_s_setprio(0);
        // refill va slot e&1, consumed 2 e-steps later
        const int g2 = (8 * i + e + 2) & 127;
        const size_t base = ((size_t)(g2 >> 1) * 32 + 8 * mq + 4 * (g2 & 1)) * 512;
        #pragma unroll
        for (int j = 0; j < 4; ++j)
          va[e & 1][j] = *(const short8*)(vroot + base + j * 512);
      }
      BARRIER();
    }
    BARRIER();   // l_lds visible

    // ---- epilogue: this wave owns ch 64*mq..+63 over all keys -> no O combine ----
    const float gam = gamma_p[0];
    float inv_l[4];
    #pragma unroll
    for (int nt = 0; nt < 4; ++nt) {
      float s = 0.f;
      #pragma unroll
      for (int pw = 0; pw < 8; ++pw)
        #pragma unroll
        for (int g = 0; g < 4; ++g)
          s += l_lds[pw][nt][g * 16 + cl];
      inv_l[nt] = 1.0f / s;
    }
    #pragma unroll
    for (int j = 0; j < 4; ++j) {
      #pragma unroll
      for (int nt = 0; nt < 4; ++nt) {
        #pragma unroll
        for (int r = 0; r < 4; ++r) {
          const int ch = 64 * mq + 16 * j + 4 * q4 + r;
          const int i  = i0 + 16 * nt + cl;
          const size_t idx = ((size_t)b * CC + ch) * LL + i;
          out[idx] = gam * O[j][nt][r] * inv_l[nt] + x[idx];
        }
      }
    }
  }
}

extern "C" void kernel_launch(void* const* d_in, const int* in_sizes, int n_in,
                              void* d_out, int out_size, void* d_ws, size_t ws_size,
                              hipStream_t stream) {
  const float* x     = (const float*)d_in[0];
  const float* Wq    = (const float*)d_in[1];
  const float* bq    = (const float*)d_in[2];
  const float* Wk    = (const float*)d_in[3];
  const float* bk    = (const float*)d_in[4];
  const float* Wv    = (const float*)d_in[5];
  const float* bv    = (const float*)d_in[6];
  const float* gamma = (const float*)d_in[7];
  float* out = (float*)d_out;

  // ws: qT (1MB, log2e-scaled) | kT (1MB, sigma rows) | vf (8MB, fragment-linear)
  unsigned short* qT = (unsigned short*)d_ws;
  unsigned short* kT = qT + (size_t)BB * LL * DD;
  unsigned short* vf = kT + (size_t)BB * LL * DD;
  // wf (160KB) lives in d_out; consumed by qkv, then attn overwrites d_out
  unsigned short* wf = (unsigned short*)d_out;

  wprep_kernel<<<40, 256, 0, stream>>>(Wq, Wk, Wv, wf);
  qkv_kernel<<<512, 512, 0, stream>>>(x, wf, bq, bk, bv, qT, kT, vf);
  attn_kernel<<<256, 768, 0, stream>>>(qT, kT, vf, x, gamma, out);
}